// Round 1
// 1284.827 us; speedup vs baseline: 1.2609x; 1.2609x over previous
//
#include <hip/hip_runtime.h>
#include <stdint.h>

// Problem constants
#define BB   4
#define SS   2048
#define HIDD 2048
#define NH   16
#define HD   128

typedef float  floatx4 __attribute__((ext_vector_type(4)));
typedef __bf16 bf16x8  __attribute__((ext_vector_type(8)));
typedef unsigned short ushort8  __attribute__((ext_vector_type(8)));
typedef unsigned short ushort4v __attribute__((ext_vector_type(4)));

__device__ __forceinline__ uint16_t f2bf(float f) {
  uint32_t u = __builtin_bit_cast(uint32_t, f);
  u += 0x7FFFu + ((u >> 16) & 1u);   // RNE
  return (uint16_t)(u >> 16);
}

__device__ __forceinline__ floatx4 mfma16(bf16x8 a, bf16x8 b, floatx4 c) {
  return __builtin_amdgcn_mfma_f32_16x16x32_bf16(a, b, c, 0, 0, 0);
}

// async global->LDS, 16B per lane. LDS dest must be wave-uniform base + lane*16.
__device__ __forceinline__ void gload16(const void* g, void* l) {
  __builtin_amdgcn_global_load_lds(
      (__attribute__((address_space(1))) void*)g,
      (__attribute__((address_space(3))) void*)l, 16, 0, 0);
}

#if __has_builtin(__builtin_amdgcn_exp2f)
#define EXP2F(x) __builtin_amdgcn_exp2f(x)
#else
#define EXP2F(x) exp2f(x)
#endif

// ---------------- fp32 -> bf16 convert (vector x4) ----------------
__global__ void cvt_f32_bf16(const float* __restrict__ src, uint16_t* __restrict__ dst) {
  int idx = (blockIdx.x * 256 + threadIdx.x) * 4;
  const float4 v = *reinterpret_cast<const float4*>(src + idx);
  ushort4v o = { f2bf(v.x), f2bf(v.y), f2bf(v.z), f2bf(v.w) };
  *reinterpret_cast<ushort4v*>(dst + idx) = o;
}

// ---------------- bf16 GEMM: C[M,N] = A[M,K] * W[N,K]^T ----------------
// 128x128 block tile, 4 waves in 2x2 grid, each wave 64x64 via 4x4 MFMA tiles.
// LDS layout: element (row, k) at row*32 + ((kc ^ ((row>>1)&3))*8 + (k&7)),
// kc = k>>3. Staged with global_load_lds width=16: LDS dest is LINEAR in lane
// order (lane t -> byte t*16 within its half-tile); the swizzle is applied to
// the GLOBAL source address instead (kc = skc ^ ((srow>>1)&3); invariant for
// row and row+64 since 64>>1 is a multiple of 4). Frag reads unchanged.
// modes: 0=Q (bf16 [B,H,S,D], scaled) 1=K (bf16 [B,H,S,D] + fp32 cache c=0)
//        2=V (bf16 [B,H,D,S] + fp32 cache c=1) 3=O (fp32 [M,N])
__global__ __launch_bounds__(256) void gemm_bf16(
    const uint16_t* __restrict__ A,
    const uint16_t* __restrict__ Bw,
    uint16_t* __restrict__ outb,
    float* __restrict__ outf,
    int mode, float scl)
{
  __shared__ alignas(16) uint16_t lsA[128 * 32];
  __shared__ alignas(16) uint16_t lsB[128 * 32];

  const int t    = threadIdx.x;
  const int lane = t & 63;
  const int wv   = t >> 6;
  const int wx   = wv & 1;
  const int wy   = wv >> 1;
  const int l15  = lane & 15;
  const int lk   = lane >> 4;
  const int m0   = blockIdx.y * 128;
  const int n0   = blockIdx.x * 128;

  const int srow = t >> 2;                     // staging row (0..63), +64 on 2nd chunk
  const int skc  = t & 3;                      // staging k-slot (LDS position)
  const int kc   = skc ^ ((srow >> 1) & 3);    // pre-swizzled global k-chunk

  floatx4 acc[4][4];
  #pragma unroll
  for (int i = 0; i < 4; i++)
    #pragma unroll
    for (int j = 0; j < 4; j++) acc[i][j] = floatx4{0.f, 0.f, 0.f, 0.f};

  const uint16_t* Ag = A  + (size_t)m0 * HIDD;
  const uint16_t* Bg = Bw + (size_t)n0 * HIDD;

  for (int k0 = 0; k0 < HIDD; k0 += 32) {
    #pragma unroll
    for (int i = 0; i < 2; ++i) {
      int row = srow + i * 64;
      gload16(Ag + (size_t)row * HIDD + k0 + kc * 8, &lsA[row * 32 + skc * 8]);
      gload16(Bg + (size_t)row * HIDD + k0 + kc * 8, &lsB[row * 32 + skc * 8]);
    }
    __syncthreads();   // compiler drains vmcnt before s_barrier -> tiles ready

    bf16x8 af[4], bf[4];
    #pragma unroll
    for (int mi = 0; mi < 4; mi++) {
      int row = wy * 64 + mi * 16 + l15;
      af[mi] = *reinterpret_cast<const bf16x8*>(&lsA[row * 32 + ((lk ^ ((row >> 1) & 3)) << 3)]);
    }
    #pragma unroll
    for (int nj = 0; nj < 4; nj++) {
      int row = wx * 64 + nj * 16 + l15;
      bf[nj] = *reinterpret_cast<const bf16x8*>(&lsB[row * 32 + ((lk ^ ((row >> 1) & 3)) << 3)]);
    }
    #pragma unroll
    for (int mi = 0; mi < 4; mi++)
      #pragma unroll
      for (int nj = 0; nj < 4; nj++)
        acc[mi][nj] = mfma16(af[mi], bf[nj], acc[mi][nj]);
    __syncthreads();
  }

  // Epilogue. C layout: col = lane&15, row = (lane>>4)*4 + reg  [verified m89/m91]
  #pragma unroll
  for (int mi = 0; mi < 4; mi++) {
    int rbase = m0 + wy * 64 + mi * 16 + lk * 4;
    #pragma unroll
    for (int nj = 0; nj < 4; nj++) {
      int col = n0 + wx * 64 + nj * 16 + l15;
      floatx4 v = acc[mi][nj];
      #pragma unroll
      for (int r = 0; r < 4; r++) {
        int rr = rbase + r;
        float val = v[r] * scl;
        int b_ = rr >> 11, s_ = rr & 2047;
        int h_ = col >> 7, d_ = col & 127;
        size_t bh = (size_t)(b_ * NH + h_);
        if (mode == 0) {
          outb[(bh * SS + s_) * HD + d_] = f2bf(val);
        } else if (mode == 1) {
          outb[(bh * SS + s_) * HD + d_] = f2bf(val);
          outf[((bh * 2 + 0) * SS + s_) * HD + d_] = val;
        } else if (mode == 2) {
          outb[(bh * HD + d_) * SS + s_] = f2bf(val);
          outf[((bh * 2 + 1) * SS + s_) * HD + d_] = val;
        } else {
          outf[(size_t)rr * HIDD + col] = val;
        }
      }
    }
  }
}

// ---------------- causal flash attention v2 ----------------
// grid (S/128, B*H), 256 thr = 4 waves. Wave w owns q rows qblk*128+w*32..+31
// as two 16-row MFMA tiles (m=0,1) -> two independent softmax chains per wave.
// K tile (32x128) and V^T tile (128x32) staged in LDS per block via
// global_load_lds (shared by all 4 waves), chunk-XOR swizzled so the 16-row
// stride-256B/64B frag reads are conflict-lean.
// KVBLK=32 divides the 32-row wave stride -> only the diagonal tile is masked;
// waves past their causal extent skip compute (but keep barriers).
// q pre-scaled by D^-0.5*log2(e) -> softmax in exp2 domain.
__global__ __launch_bounds__(256) void attn_fwd(
    const uint16_t* __restrict__ qb,
    const uint16_t* __restrict__ kb,
    const uint16_t* __restrict__ vtb,
    uint16_t* __restrict__ ctxb)
{
  const int qblk = blockIdx.x;
  const int bh   = blockIdx.y;
  const int b    = bh >> 4;
  const int h    = bh & 15;
  const int t    = threadIdx.x;
  const int lane = t & 63;
  const int w    = t >> 6;
  const int l15  = lane & 15;
  const int lk   = lane >> 4;

  const int qrow_w = qblk * 128 + w * 32;

  // LDS: K tile 8KB (chunk (row,kc) at elem row*128 + (kc^(row&7))*8),
  //      V tile 8KB (chunk (row,kc) at elem row*32  + (kc^(row&3))*8),
  //      P buffers 10KB. Total 26KB.
  __shared__ alignas(16) uint16_t lsK[32 * 128];
  __shared__ alignas(16) uint16_t lsV[128 * 32];
  __shared__ alignas(16) uint16_t pls[4][2][16 * 40];

  const uint16_t* qptr = qb  + ((size_t)bh * SS + qrow_w) * HD;
  const uint16_t* kg   = kb  + (size_t)bh * SS * HD;
  const uint16_t* vg   = vtb + (size_t)bh * (size_t)HD * SS;

  bf16x8 qf[2][4];
  #pragma unroll
  for (int m = 0; m < 2; ++m)
    #pragma unroll
    for (int c = 0; c < 4; ++c)
      qf[m][c] = *reinterpret_cast<const bf16x8*>(
          qptr + (size_t)(m * 16 + l15) * HD + c * 32 + lk * 8);

  floatx4 o[2][8];
  #pragma unroll
  for (int m = 0; m < 2; ++m)
    #pragma unroll
    for (int i = 0; i < 8; i++) o[m][i] = floatx4{0.f, 0.f, 0.f, 0.f};
  float m2[2][4], lsum[2][4];
  #pragma unroll
  for (int m = 0; m < 2; ++m)
    #pragma unroll
    for (int r = 0; r < 4; r++) { m2[m][r] = -__builtin_inff(); lsum[m][r] = 0.f; }

  const int ktiles = qblk * 4 + 4;
  for (int kt = 0; kt < ktiles; ++kt) {
    const int kbase = kt * 32;

    // ---- stage K (32x128) + V (128x32) into LDS, all 256 threads ----
    // Linear LDS in lane order; swizzle applied to the GLOBAL chunk index.
    #pragma unroll
    for (int j = 0; j < 2; ++j) {
      int g  = j * 256 + t;
      int kr = g >> 4, ks = g & 15;              // K: 32 rows x 16 chunks
      gload16(kg + (size_t)(kbase + kr) * HD + (ks ^ (kr & 7)) * 8, &lsK[g * 8]);
      int vr = g >> 2, vs = g & 3;               // V: 128 rows x 4 chunks
      gload16(vg + (size_t)vr * SS + kbase + (vs ^ (vr & 3)) * 8, &lsV[g * 8]);
    }
    __syncthreads();   // drains vmcnt -> tile ready for all waves

    if (kbase <= qrow_w + 31) {
      // ---- QK^T: 16 MFMAs, K frags shared across m ----
      floatx4 sa[2], sb[2];
      sa[0] = floatx4{0.f,0.f,0.f,0.f}; sa[1] = floatx4{0.f,0.f,0.f,0.f};
      sb[0] = floatx4{0.f,0.f,0.f,0.f}; sb[1] = floatx4{0.f,0.f,0.f,0.f};
      #pragma unroll
      for (int c = 0; c < 4; ++c) {
        int kr0 = l15, kr1 = 16 + l15;
        bf16x8 k0 = *reinterpret_cast<const bf16x8*>(
            &lsK[kr0 * 128 + (((c * 4 + lk) ^ (kr0 & 7)) * 8)]);
        bf16x8 k1 = *reinterpret_cast<const bf16x8*>(
            &lsK[kr1 * 128 + (((c * 4 + lk) ^ (kr1 & 7)) * 8)]);
        sa[0] = mfma16(qf[0][c], k0, sa[0]);
        sb[0] = mfma16(qf[0][c], k1, sb[0]);
        sa[1] = mfma16(qf[1][c], k0, sa[1]);
        sb[1] = mfma16(qf[1][c], k1, sb[1]);
      }

      bf16x8 pf[2];
      #pragma unroll
      for (int m = 0; m < 2; ++m) {
        const int qrm = qrow_w + m * 16;
        if (kbase + 31 > qrm) {  // diagonal tile: causal mask (key > query -> -inf)
          #pragma unroll
          for (int r = 0; r < 4; r++) {
            int qr = qrm + lk * 4 + r;
            if (kbase + l15 > qr)      sa[m][r] = -__builtin_inff();
            if (kbase + 16 + l15 > qr) sb[m][r] = -__builtin_inff();
          }
        }
        float alpha[4];
        #pragma unroll
        for (int r = 0; r < 4; r++) {
          float mt = fmaxf(sa[m][r], sb[m][r]);
          #pragma unroll
          for (int off = 1; off < 16; off <<= 1) mt = fmaxf(mt, __shfl_xor(mt, off));
          float mn = fmaxf(m2[m][r], mt);
          alpha[r] = EXP2F(m2[m][r] - mn);
          m2[m][r] = mn;
        }
        uint16_t* pbuf = pls[w][m];
        #pragma unroll
        for (int r = 0; r < 4; r++) {
          float p0 = EXP2F(sa[m][r] - m2[m][r]);
          float p1 = EXP2F(sb[m][r] - m2[m][r]);
          float ps = p0 + p1;
          #pragma unroll
          for (int off = 1; off < 16; off <<= 1) ps += __shfl_xor(ps, off);
          lsum[m][r] = lsum[m][r] * alpha[r] + ps;
          pbuf[(lk * 4 + r) * 40 + l15]      = f2bf(p0);
          pbuf[(lk * 4 + r) * 40 + 16 + l15] = f2bf(p1);
        }
        #pragma unroll
        for (int i = 0; i < 8; i++)
          #pragma unroll
          for (int r = 0; r < 4; r++) o[m][i][r] *= alpha[r];

        // P: C-layout -> A-layout via LDS round trip (wave-private, lockstep)
        asm volatile("s_waitcnt lgkmcnt(0)" ::: "memory");
        pf[m] = *reinterpret_cast<const bf16x8*>(pbuf + l15 * 40 + lk * 8);
      }

      // ---- PV: 16 MFMAs, V frags shared across m ----
      #pragma unroll
      for (int i = 0; i < 8; i++) {
        int vrr = i * 16 + l15;
        bf16x8 vf = *reinterpret_cast<const bf16x8*>(
            &lsV[vrr * 32 + ((lk ^ (vrr & 3)) * 8)]);
        o[0][i] = mfma16(pf[0], vf, o[0][i]);
        o[1][i] = mfma16(pf[1], vf, o[1][i]);
      }
    }
    __syncthreads();   // all waves done reading before next stage overwrites
  }

  #pragma unroll
  for (int m = 0; m < 2; ++m) {
    float inv[4];
    #pragma unroll
    for (int r = 0; r < 4; r++) inv[r] = 1.0f / lsum[m][r];
    uint16_t* cdst = ctxb + ((size_t)b * SS + qrow_w + m * 16) * HIDD + h * HD;
    #pragma unroll
    for (int i = 0; i < 8; i++)
      #pragma unroll
      for (int r = 0; r < 4; r++)
        cdst[(size_t)(lk * 4 + r) * HIDD + i * 16 + l15] = f2bf(o[m][i][r] * inv[r]);
  }
}

// ---------------- launch ----------------
extern "C" void kernel_launch(void* const* d_in, const int* in_sizes, int n_in,
                              void* d_out, int out_size, void* d_ws, size_t ws_size,
                              hipStream_t stream) {
  const float* x  = (const float*)d_in[0];
  const float* Wq = (const float*)d_in[1];
  const float* Wk = (const float*)d_in[2];
  const float* Wv = (const float*)d_in[3];
  const float* Wo = (const float*)d_in[4];
  float* out = (float*)d_out;
  float* kv  = out + (size_t)BB * SS * HIDD;  // kv cache region

  uint8_t* ws = (uint8_t*)d_ws;
  // byte offsets (total 160 MiB)
  uint16_t* xb  = (uint16_t*)(ws);              // 32 MiB; reused as ctx after attn
  uint16_t* qb  = (uint16_t*)(ws + 33554432);
  uint16_t* kb  = (uint16_t*)(ws + 67108864);
  uint16_t* vtb = (uint16_t*)(ws + 100663296);
  uint16_t* wqb = (uint16_t*)(ws + 134217728);
  uint16_t* wkb = (uint16_t*)(ws + 142606336);
  uint16_t* wvb = (uint16_t*)(ws + 150994944);
  uint16_t* wob = (uint16_t*)(ws + 159383552);

  const float QSCALE = 0.08838834764831845f * 1.4426950408889634f; // D^-0.5 * log2(e)

  cvt_f32_bf16<<<16384, 256, 0, stream>>>(x,  xb);
  cvt_f32_bf16<<<4096,  256, 0, stream>>>(Wq, wqb);
  cvt_f32_bf16<<<4096,  256, 0, stream>>>(Wk, wkb);
  cvt_f32_bf16<<<4096,  256, 0, stream>>>(Wv, wvb);
  cvt_f32_bf16<<<4096,  256, 0, stream>>>(Wo, wob);

  dim3 ggrid(HIDD / 128, (BB * SS) / 128);  // (16, 64)
  gemm_bf16<<<ggrid, 256, 0, stream>>>(xb, wqb, qb,  nullptr, 0, QSCALE);
  gemm_bf16<<<ggrid, 256, 0, stream>>>(xb, wkb, kb,  kv,      1, 1.0f);
  gemm_bf16<<<ggrid, 256, 0, stream>>>(xb, wvb, vtb, kv,      2, 1.0f);

  attn_fwd<<<dim3(SS / 128, BB * NH), 256, 0, stream>>>(qb, kb, vtb, xb /*ctx*/);

  gemm_bf16<<<ggrid, 256, 0, stream>>>(xb, wob, nullptr, out, 3, 1.0f);
}

// Round 2
// 1150.852 us; speedup vs baseline: 1.4076x; 1.1164x over previous
//
#include <hip/hip_runtime.h>
#include <stdint.h>

// Problem constants
#define BB   4
#define SS   2048
#define HIDD 2048
#define NH   16
#define HD   128

typedef float  floatx4 __attribute__((ext_vector_type(4)));
typedef __bf16 bf16x8  __attribute__((ext_vector_type(8)));
typedef unsigned short ushort8  __attribute__((ext_vector_type(8)));
typedef unsigned short ushort4v __attribute__((ext_vector_type(4)));

__device__ __forceinline__ uint16_t f2bf(float f) {
  uint32_t u = __builtin_bit_cast(uint32_t, f);
  u += 0x7FFFu + ((u >> 16) & 1u);   // RNE
  return (uint16_t)(u >> 16);
}

__device__ __forceinline__ floatx4 mfma16(bf16x8 a, bf16x8 b, floatx4 c) {
  return __builtin_amdgcn_mfma_f32_16x16x32_bf16(a, b, c, 0, 0, 0);
}

// async global->LDS, 16B per lane. LDS dest must be wave-uniform base + lane*16.
__device__ __forceinline__ void gload16(const void* g, void* l) {
  __builtin_amdgcn_global_load_lds(
      (__attribute__((address_space(1))) void*)g,
      (__attribute__((address_space(3))) void*)l, 16, 0, 0);
}

#if __has_builtin(__builtin_amdgcn_exp2f)
#define EXP2F(x) __builtin_amdgcn_exp2f(x)
#else
#define EXP2F(x) exp2f(x)
#endif

// ---------------- fp32 -> bf16 convert (vector x4) ----------------
__global__ void cvt_f32_bf16(const float* __restrict__ src, uint16_t* __restrict__ dst) {
  int idx = (blockIdx.x * 256 + threadIdx.x) * 4;
  const float4 v = *reinterpret_cast<const float4*>(src + idx);
  ushort4v o = { f2bf(v.x), f2bf(v.y), f2bf(v.z), f2bf(v.w) };
  *reinterpret_cast<ushort4v*>(dst + idx) = o;
}

// ---------------- bf16 GEMM: C[M,N] = A[M,K] * W[N,K]^T ----------------
// 128x128 block tile, 4 waves in 2x2 grid, each wave 64x64 via 4x4 MFMA tiles.
// LDS layout: element (row, k) at row*32 + ((kc ^ ((row>>1)&3))*8 + (k&7)),
// kc = k>>3. Staged with global_load_lds width=16: LDS dest LINEAR in lane
// order; the swizzle is applied to the GLOBAL source address instead.
// modes: 0=Q (bf16 [B,H,S,D], scaled) 1=K (bf16 [B,H,S,D] + fp32 cache c=0)
//        2=V (bf16 [B,H,D,S] + fp32 cache c=1) 3=O (fp32 [M,N])
__global__ __launch_bounds__(256) void gemm_bf16(
    const uint16_t* __restrict__ A,
    const uint16_t* __restrict__ Bw,
    uint16_t* __restrict__ outb,
    float* __restrict__ outf,
    int mode, float scl)
{
  __shared__ alignas(16) uint16_t lsA[128 * 32];
  __shared__ alignas(16) uint16_t lsB[128 * 32];

  const int t    = threadIdx.x;
  const int lane = t & 63;
  const int wv   = t >> 6;
  const int wx   = wv & 1;
  const int wy   = wv >> 1;
  const int l15  = lane & 15;
  const int lk   = lane >> 4;
  const int m0   = blockIdx.y * 128;
  const int n0   = blockIdx.x * 128;

  const int srow = t >> 2;                     // staging row (0..63), +64 on 2nd chunk
  const int skc  = t & 3;                      // staging k-slot (LDS position)
  const int kc   = skc ^ ((srow >> 1) & 3);    // pre-swizzled global k-chunk

  floatx4 acc[4][4];
  #pragma unroll
  for (int i = 0; i < 4; i++)
    #pragma unroll
    for (int j = 0; j < 4; j++) acc[i][j] = floatx4{0.f, 0.f, 0.f, 0.f};

  const uint16_t* Ag = A  + (size_t)m0 * HIDD;
  const uint16_t* Bg = Bw + (size_t)n0 * HIDD;

  for (int k0 = 0; k0 < HIDD; k0 += 32) {
    #pragma unroll
    for (int i = 0; i < 2; ++i) {
      int row = srow + i * 64;
      gload16(Ag + (size_t)row * HIDD + k0 + kc * 8, &lsA[row * 32 + skc * 8]);
      gload16(Bg + (size_t)row * HIDD + k0 + kc * 8, &lsB[row * 32 + skc * 8]);
    }
    __syncthreads();   // compiler drains vmcnt before s_barrier -> tiles ready

    bf16x8 af[4], bf[4];
    #pragma unroll
    for (int mi = 0; mi < 4; mi++) {
      int row = wy * 64 + mi * 16 + l15;
      af[mi] = *reinterpret_cast<const bf16x8*>(&lsA[row * 32 + ((lk ^ ((row >> 1) & 3)) << 3)]);
    }
    #pragma unroll
    for (int nj = 0; nj < 4; nj++) {
      int row = wx * 64 + nj * 16 + l15;
      bf[nj] = *reinterpret_cast<const bf16x8*>(&lsB[row * 32 + ((lk ^ ((row >> 1) & 3)) << 3)]);
    }
    #pragma unroll
    for (int mi = 0; mi < 4; mi++)
      #pragma unroll
      for (int nj = 0; nj < 4; nj++)
        acc[mi][nj] = mfma16(af[mi], bf[nj], acc[mi][nj]);
    __syncthreads();
  }

  // Epilogue. C layout: col = lane&15, row = (lane>>4)*4 + reg  [verified m89/m91]
  #pragma unroll
  for (int mi = 0; mi < 4; mi++) {
    int rbase = m0 + wy * 64 + mi * 16 + lk * 4;
    #pragma unroll
    for (int nj = 0; nj < 4; nj++) {
      int col = n0 + wx * 64 + nj * 16 + l15;
      floatx4 v = acc[mi][nj];
      #pragma unroll
      for (int r = 0; r < 4; r++) {
        int rr = rbase + r;
        float val = v[r] * scl;
        int b_ = rr >> 11, s_ = rr & 2047;
        int h_ = col >> 7, d_ = col & 127;
        size_t bh = (size_t)(b_ * NH + h_);
        if (mode == 0) {
          outb[(bh * SS + s_) * HD + d_] = f2bf(val);
        } else if (mode == 1) {
          outb[(bh * SS + s_) * HD + d_] = f2bf(val);
          outf[((bh * 2 + 0) * SS + s_) * HD + d_] = val;
        } else if (mode == 2) {
          outb[(bh * HD + d_) * SS + s_] = f2bf(val);
          outf[((bh * 2 + 1) * SS + s_) * HD + d_] = val;
        } else {
          outf[(size_t)rr * HIDD + col] = val;
        }
      }
    }
  }
}

// ---------------- causal flash attention v3 ----------------
// Flat 1-D grid of 1024 blocks, 256 thr = 4 waves. Block id decode:
//   xcd = id&7 (XCD-cluster: all q-blocks of a bh on one XCD's L2),
//   within XCD: bh-major, qblk DESCENDING (heavy blocks dispatch first ->
//   short tail under the causal work imbalance).
// Wave w owns q rows qblk*128 + w*32 .. +31 as two 16-row MFMA tiles.
// K (32x128) and V^T (128x32) tiles DOUBLE-BUFFERED in LDS: tile kt+1's
// global_load_lds is issued before computing tile kt; the single barrier at
// iteration end drains it (T3 minimum 2-phase -> staging latency hides
// under QK^T/softmax/PV).
// Defer-max (T13, THR=8 in exp2 domain): skip O-rescale when the running max
// doesn't grow by >8 -> P bounded by 2^8, f32 lsum safe.
// q pre-scaled by D^-0.5*log2(e) -> softmax in exp2 domain.
__global__ __launch_bounds__(256) void attn_fwd(
    const uint16_t* __restrict__ qb,
    const uint16_t* __restrict__ kb,
    const uint16_t* __restrict__ vtb,
    uint16_t* __restrict__ ctxb)
{
  const int id   = blockIdx.x;
  const int xcd  = id & 7;
  const int kk   = id >> 3;
  const int ybh  = kk >> 4;
  const int qblk = 15 - (kk & 15);        // heavy-first
  const int bh   = (ybh << 3) | xcd;      // XCD-clustered bh
  const int b    = bh >> 4;
  const int h    = bh & 15;
  const int t    = threadIdx.x;
  const int lane = t & 63;
  const int w    = t >> 6;
  const int l15  = lane & 15;
  const int lk   = lane >> 4;

  const int qrow_w = qblk * 128 + w * 32;

  // LDS: 2x K tile 8KB + 2x V tile 8KB + P buffers 10KB = 42KB (3 blocks/CU).
  __shared__ alignas(16) uint16_t lsK[2][32 * 128];
  __shared__ alignas(16) uint16_t lsV[2][128 * 32];
  __shared__ alignas(16) uint16_t pls[4][2][16 * 40];

  const uint16_t* qptr = qb  + ((size_t)bh * SS + qrow_w) * HD;
  const uint16_t* kg   = kb  + (size_t)bh * SS * HD;
  const uint16_t* vg   = vtb + (size_t)bh * (size_t)HD * SS;

  bf16x8 qf[2][4];
  #pragma unroll
  for (int m = 0; m < 2; ++m)
    #pragma unroll
    for (int c = 0; c < 4; ++c)
      qf[m][c] = *reinterpret_cast<const bf16x8*>(
          qptr + (size_t)(m * 16 + l15) * HD + c * 32 + lk * 8);

  floatx4 o[2][8];
  #pragma unroll
  for (int m = 0; m < 2; ++m)
    #pragma unroll
    for (int i = 0; i < 8; i++) o[m][i] = floatx4{0.f, 0.f, 0.f, 0.f};
  float m2[2][4], lsum[2][4];
  #pragma unroll
  for (int m = 0; m < 2; ++m)
    #pragma unroll
    for (int r = 0; r < 4; r++) { m2[m][r] = -__builtin_inff(); lsum[m][r] = 0.f; }

  // stage K (32x128) + V (128x32) for tile kt2 into LDS buffer bi.
  // Linear LDS in lane order; chunk-XOR swizzle applied to GLOBAL source.
  auto stage = [&](int bi, int kt2) {
    const int kb2 = kt2 * 32;
    #pragma unroll
    for (int j = 0; j < 2; ++j) {
      int g  = j * 256 + t;
      int kr = g >> 4, ks = g & 15;              // K: 32 rows x 16 chunks
      gload16(kg + (size_t)(kb2 + kr) * HD + ((ks ^ (kr & 7)) << 3), &lsK[bi][g * 8]);
      int vr = g >> 2, vs = g & 3;               // V: 128 rows x 4 chunks
      gload16(vg + (size_t)vr * SS + kb2 + ((vs ^ (vr & 3)) << 3), &lsV[bi][g * 8]);
    }
  };

  const int ktiles = qblk * 4 + 4;
  stage(0, 0);
  __syncthreads();   // drain prologue stage

  for (int kt = 0; kt < ktiles; ++kt) {
    const int cur   = kt & 1;
    const int kbase = kt * 32;

    // issue next tile's loads BEFORE compute; end-of-iter barrier drains them
    if (kt + 1 < ktiles) stage(cur ^ 1, kt + 1);

    if (kbase <= qrow_w + 31) {
      // ---- QK^T: 16 MFMAs, K frags shared across m ----
      floatx4 sa[2], sb[2];
      sa[0] = floatx4{0.f,0.f,0.f,0.f}; sa[1] = floatx4{0.f,0.f,0.f,0.f};
      sb[0] = floatx4{0.f,0.f,0.f,0.f}; sb[1] = floatx4{0.f,0.f,0.f,0.f};
      #pragma unroll
      for (int c = 0; c < 4; ++c) {
        int kr0 = l15, kr1 = 16 + l15;
        bf16x8 k0 = *reinterpret_cast<const bf16x8*>(
            &lsK[cur][kr0 * 128 + (((c * 4 + lk) ^ (kr0 & 7)) * 8)]);
        bf16x8 k1 = *reinterpret_cast<const bf16x8*>(
            &lsK[cur][kr1 * 128 + (((c * 4 + lk) ^ (kr1 & 7)) * 8)]);
        sa[0] = mfma16(qf[0][c], k0, sa[0]);
        sb[0] = mfma16(qf[0][c], k1, sb[0]);
        sa[1] = mfma16(qf[1][c], k0, sa[1]);
        sb[1] = mfma16(qf[1][c], k1, sb[1]);
      }

      bf16x8 pf[2];
      #pragma unroll
      for (int m = 0; m < 2; ++m) {
        const int qrm = qrow_w + m * 16;
        if (kbase + 31 > qrm) {  // diagonal tile: causal mask (key > query -> -inf)
          #pragma unroll
          for (int r = 0; r < 4; r++) {
            int qr = qrm + lk * 4 + r;
            if (kbase + l15 > qr)      sa[m][r] = -__builtin_inff();
            if (kbase + 16 + l15 > qr) sb[m][r] = -__builtin_inff();
          }
        }
        float alpha[4];
        #pragma unroll
        for (int r = 0; r < 4; r++) {
          float mt = fmaxf(sa[m][r], sb[m][r]);
          #pragma unroll
          for (int off = 1; off < 16; off <<= 1) mt = fmaxf(mt, __shfl_xor(mt, off));
          float mo = m2[m][r];
          float mn = (mt > mo + 8.f) ? mt : mo;   // defer-max: keep mo if growth <= 8
          alpha[r] = EXP2F(mo - mn);               // exactly 1.0 when deferred
          m2[m][r] = mn;
        }
        uint16_t* pbuf = pls[w][m];
        #pragma unroll
        for (int r = 0; r < 4; r++) {
          float p0 = EXP2F(sa[m][r] - m2[m][r]);
          float p1 = EXP2F(sb[m][r] - m2[m][r]);
          float ps = p0 + p1;
          #pragma unroll
          for (int off = 1; off < 16; off <<= 1) ps += __shfl_xor(ps, off);
          lsum[m][r] = lsum[m][r] * alpha[r] + ps;
          pbuf[(lk * 4 + r) * 40 + l15]      = f2bf(p0);
          pbuf[(lk * 4 + r) * 40 + 16 + l15] = f2bf(p1);
        }
        if (__any(alpha[0] != 1.f || alpha[1] != 1.f ||
                  alpha[2] != 1.f || alpha[3] != 1.f)) {
          #pragma unroll
          for (int i = 0; i < 8; i++)
            #pragma unroll
            for (int r = 0; r < 4; r++) o[m][i][r] *= alpha[r];
        }

        // P: C-layout -> A-layout via LDS round trip (wave-private, lockstep)
        asm volatile("s_waitcnt lgkmcnt(0)" ::: "memory");
        pf[m] = *reinterpret_cast<const bf16x8*>(pbuf + l15 * 40 + lk * 8);
      }

      // ---- PV: 16 MFMAs, V frags shared across m ----
      #pragma unroll
      for (int i = 0; i < 8; i++) {
        int vrr = i * 16 + l15;
        bf16x8 vf = *reinterpret_cast<const bf16x8*>(
            &lsV[cur][vrr * 32 + ((lk ^ (vrr & 3)) * 8)]);
        o[0][i] = mfma16(pf[0], vf, o[0][i]);
        o[1][i] = mfma16(pf[1], vf, o[1][i]);
      }
    }
    __syncthreads();  // drains next-tile loads; fences buf reuse
  }

  #pragma unroll
  for (int m = 0; m < 2; ++m) {
    float inv[4];
    #pragma unroll
    for (int r = 0; r < 4; r++) inv[r] = 1.0f / lsum[m][r];
    uint16_t* cdst = ctxb + ((size_t)b * SS + qrow_w + m * 16) * HIDD + h * HD;
    #pragma unroll
    for (int i = 0; i < 8; i++)
      #pragma unroll
      for (int r = 0; r < 4; r++)
        cdst[(size_t)(lk * 4 + r) * HIDD + i * 16 + l15] = f2bf(o[m][i][r] * inv[r]);
  }
}

// ---------------- launch ----------------
extern "C" void kernel_launch(void* const* d_in, const int* in_sizes, int n_in,
                              void* d_out, int out_size, void* d_ws, size_t ws_size,
                              hipStream_t stream) {
  const float* x  = (const float*)d_in[0];
  const float* Wq = (const float*)d_in[1];
  const float* Wk = (const float*)d_in[2];
  const float* Wv = (const float*)d_in[3];
  const float* Wo = (const float*)d_in[4];
  float* out = (float*)d_out;
  float* kv  = out + (size_t)BB * SS * HIDD;  // kv cache region

  uint8_t* ws = (uint8_t*)d_ws;
  // byte offsets (total 160 MiB)
  uint16_t* xb  = (uint16_t*)(ws);              // 32 MiB; reused as ctx after attn
  uint16_t* qb  = (uint16_t*)(ws + 33554432);
  uint16_t* kb  = (uint16_t*)(ws + 67108864);
  uint16_t* vtb = (uint16_t*)(ws + 100663296);
  uint16_t* wqb = (uint16_t*)(ws + 134217728);
  uint16_t* wkb = (uint16_t*)(ws + 142606336);
  uint16_t* wvb = (uint16_t*)(ws + 150994944);
  uint16_t* wob = (uint16_t*)(ws + 159383552);

  const float QSCALE = 0.08838834764831845f * 1.4426950408889634f; // D^-0.5 * log2(e)

  cvt_f32_bf16<<<16384, 256, 0, stream>>>(x,  xb);
  cvt_f32_bf16<<<4096,  256, 0, stream>>>(Wq, wqb);
  cvt_f32_bf16<<<4096,  256, 0, stream>>>(Wk, wkb);
  cvt_f32_bf16<<<4096,  256, 0, stream>>>(Wv, wvb);
  cvt_f32_bf16<<<4096,  256, 0, stream>>>(Wo, wob);

  dim3 ggrid(HIDD / 128, (BB * SS) / 128);  // (16, 64)
  gemm_bf16<<<ggrid, 256, 0, stream>>>(xb, wqb, qb,  nullptr, 0, QSCALE);
  gemm_bf16<<<ggrid, 256, 0, stream>>>(xb, wkb, kb,  kv,      1, 1.0f);
  gemm_bf16<<<ggrid, 256, 0, stream>>>(xb, wvb, vtb, kv,      2, 1.0f);

  attn_fwd<<<dim3(1024), 256, 0, stream>>>(qb, kb, vtb, xb /*ctx*/);

  gemm_bf16<<<ggrid, 256, 0, stream>>>(xb, wob, nullptr, out, 3, 1.0f);
}

// Round 3
// 1117.869 us; speedup vs baseline: 1.4492x; 1.0295x over previous
//
#include <hip/hip_runtime.h>
#include <stdint.h>

// Problem constants
#define BB   4
#define SS   2048
#define HIDD 2048
#define NH   16
#define HD   128

typedef float  floatx4 __attribute__((ext_vector_type(4)));
typedef __bf16 bf16x8  __attribute__((ext_vector_type(8)));
typedef unsigned short ushort8  __attribute__((ext_vector_type(8)));
typedef unsigned short ushort4v __attribute__((ext_vector_type(4)));

__device__ __forceinline__ uint16_t f2bf(float f) {
  uint32_t u = __builtin_bit_cast(uint32_t, f);
  u += 0x7FFFu + ((u >> 16) & 1u);   // RNE
  return (uint16_t)(u >> 16);
}

__device__ __forceinline__ floatx4 mfma16(bf16x8 a, bf16x8 b, floatx4 c) {
  return __builtin_amdgcn_mfma_f32_16x16x32_bf16(a, b, c, 0, 0, 0);
}

// async global->LDS, 16B per lane. LDS dest must be wave-uniform base + lane*16.
__device__ __forceinline__ void gload16(const void* g, void* l) {
  __builtin_amdgcn_global_load_lds(
      (__attribute__((address_space(1))) void*)g,
      (__attribute__((address_space(3))) void*)l, 16, 0, 0);
}

#if __has_builtin(__builtin_amdgcn_exp2f)
#define EXP2F(x) __builtin_amdgcn_exp2f(x)
#else
#define EXP2F(x) exp2f(x)
#endif

// ---------------- fp32 -> bf16 convert (vector x4) ----------------
__global__ void cvt_f32_bf16(const float* __restrict__ src, uint16_t* __restrict__ dst) {
  int idx = (blockIdx.x * 256 + threadIdx.x) * 4;
  const float4 v = *reinterpret_cast<const float4*>(src + idx);
  ushort4v o = { f2bf(v.x), f2bf(v.y), f2bf(v.z), f2bf(v.w) };
  *reinterpret_cast<ushort4v*>(dst + idx) = o;
}

// ---------------- bf16 GEMM: C[M,N] = A[M,K] * W[N,K]^T ----------------
// 128x128 block tile, 4 waves in 2x2 grid, each wave 64x64 via 4x4 MFMA tiles.
// XCD-aware swizzle (T1): grid is 16x-cols x 64y-rows = 1024 blocks; hardware
// round-robins consecutive ids over 8 XCDs. Each XCD gets a 4-col x 32-row
// rectangle (x-fastest within) -> per-XCD hot set = 4 B-panels (2MB) + 1
// A-block (0.5MB) < 4MB L2; A-block reused across 4 consecutive blocks.
// LDS layout: element (row, k) at row*32 + ((kc ^ ((row>>1)&3))*8 + (k&7)),
// staged with global_load_lds width=16 (LDS linear, swizzle on global src).
// modes: 0=Q (bf16 [B,H,S,D], scaled) 1=K (bf16 [B,H,S,D] + fp32 cache c=0)
//        2=V (bf16 [B,H,D,S] + fp32 cache c=1) 3=O (fp32 [M,N])
__global__ __launch_bounds__(256) void gemm_bf16(
    const uint16_t* __restrict__ A,
    const uint16_t* __restrict__ Bw,
    uint16_t* __restrict__ outb,
    float* __restrict__ outf,
    int mode, float scl)
{
  __shared__ alignas(16) uint16_t lsA[128 * 32];
  __shared__ alignas(16) uint16_t lsB[128 * 32];

  const int t    = threadIdx.x;
  const int lane = t & 63;
  const int wv   = t >> 6;
  const int wx   = wv & 1;
  const int wy   = wv >> 1;
  const int l15  = lane & 15;
  const int lk   = lane >> 4;

  // XCD-clustered block remap (bijective on 16x64)
  const int id   = blockIdx.y * gridDim.x + blockIdx.x;
  const int xcd  = id & 7;
  const int lin  = id >> 3;                        // 0..127 per XCD
  const int bx   = (xcd >> 1) * 4 + (lin & 3);     // x-quad per XCD pair
  const int by   = (xcd & 1) * 32 + (lin >> 2);    // y-strip
  const int m0   = by * 128;
  const int n0   = bx * 128;

  const int srow = t >> 2;                     // staging row (0..63), +64 on 2nd chunk
  const int skc  = t & 3;                      // staging k-slot (LDS position)
  const int kc   = skc ^ ((srow >> 1) & 3);    // pre-swizzled global k-chunk

  floatx4 acc[4][4];
  #pragma unroll
  for (int i = 0; i < 4; i++)
    #pragma unroll
    for (int j = 0; j < 4; j++) acc[i][j] = floatx4{0.f, 0.f, 0.f, 0.f};

  const uint16_t* Ag = A  + (size_t)m0 * HIDD;
  const uint16_t* Bg = Bw + (size_t)n0 * HIDD;

  for (int k0 = 0; k0 < HIDD; k0 += 32) {
    #pragma unroll
    for (int i = 0; i < 2; ++i) {
      int row = srow + i * 64;
      gload16(Ag + (size_t)row * HIDD + k0 + kc * 8, &lsA[row * 32 + skc * 8]);
      gload16(Bg + (size_t)row * HIDD + k0 + kc * 8, &lsB[row * 32 + skc * 8]);
    }
    __syncthreads();   // compiler drains vmcnt before s_barrier -> tiles ready

    bf16x8 af[4], bf[4];
    #pragma unroll
    for (int mi = 0; mi < 4; mi++) {
      int row = wy * 64 + mi * 16 + l15;
      af[mi] = *reinterpret_cast<const bf16x8*>(&lsA[row * 32 + ((lk ^ ((row >> 1) & 3)) << 3)]);
    }
    #pragma unroll
    for (int nj = 0; nj < 4; nj++) {
      int row = wx * 64 + nj * 16 + l15;
      bf[nj] = *reinterpret_cast<const bf16x8*>(&lsB[row * 32 + ((lk ^ ((row >> 1) & 3)) << 3)]);
    }
    #pragma unroll
    for (int mi = 0; mi < 4; mi++)
      #pragma unroll
      for (int nj = 0; nj < 4; nj++)
        acc[mi][nj] = mfma16(af[mi], bf[nj], acc[mi][nj]);
    __syncthreads();
  }

  // Epilogue. C layout: col = lane&15, row = (lane>>4)*4 + reg  [verified m89/m91]
  #pragma unroll
  for (int mi = 0; mi < 4; mi++) {
    int rbase = m0 + wy * 64 + mi * 16 + lk * 4;
    #pragma unroll
    for (int nj = 0; nj < 4; nj++) {
      int col = n0 + wx * 64 + nj * 16 + l15;
      floatx4 v = acc[mi][nj];
      #pragma unroll
      for (int r = 0; r < 4; r++) {
        int rr = rbase + r;
        float val = v[r] * scl;
        int b_ = rr >> 11, s_ = rr & 2047;
        int h_ = col >> 7, d_ = col & 127;
        size_t bh = (size_t)(b_ * NH + h_);
        if (mode == 0) {
          outb[(bh * SS + s_) * HD + d_] = f2bf(val);
        } else if (mode == 1) {
          outb[(bh * SS + s_) * HD + d_] = f2bf(val);
          outf[((bh * 2 + 0) * SS + s_) * HD + d_] = val;
        } else if (mode == 2) {
          outb[(bh * HD + d_) * SS + s_] = f2bf(val);
          outf[((bh * 2 + 1) * SS + s_) * HD + d_] = val;
        } else {
          outf[(size_t)rr * HIDD + col] = val;
        }
      }
    }
  }
}

// ---------------- causal flash attention v4 ----------------
// Flat 1-D grid of 1024 blocks, 256 thr = 4 waves. Block id decode:
//   xcd = id&7 (XCD-cluster: all q-blocks of a bh on one XCD's L2),
//   within XCD: bh-major, qblk DESCENDING (heavy-first).
// Wave w owns q rows qblk*128 + w*32 .. +31 as two 16-row MFMA tiles.
// K (32x128) and V^T (128x32) double-buffered in LDS via global_load_lds.
// T4 counted vmcnt: per iteration -> issue stage(t+1) [4 loads/thread], then
// s_waitcnt vmcnt(4) (waits tile t's loads, issued a FULL iteration earlier;
// tile t+1's 4 stay in flight), raw s_barrier, compute, raw s_barrier.
// No vmcnt(0) drain in the main loop -> staging latency fully hidden.
// Single merged lgkmcnt(0) for both m P round-trips.
// Defer-max (T13): skip O-rescale when running max grows by <= 8 (exp2 dom).
__global__ __launch_bounds__(256) void attn_fwd(
    const uint16_t* __restrict__ qb,
    const uint16_t* __restrict__ kb,
    const uint16_t* __restrict__ vtb,
    uint16_t* __restrict__ ctxb)
{
  const int id   = blockIdx.x;
  const int xcd  = id & 7;
  const int kk   = id >> 3;
  const int ybh  = kk >> 4;
  const int qblk = 15 - (kk & 15);        // heavy-first
  const int bh   = (ybh << 3) | xcd;      // XCD-clustered bh
  const int b    = bh >> 4;
  const int h    = bh & 15;
  const int t    = threadIdx.x;
  const int lane = t & 63;
  const int w    = t >> 6;
  const int l15  = lane & 15;
  const int lk   = lane >> 4;

  const int qrow_w = qblk * 128 + w * 32;

  // LDS: 2x K tile 8KB + 2x V tile 8KB + P buffers 10KB = 42KB (3 blocks/CU).
  __shared__ alignas(16) uint16_t lsK[2][32 * 128];
  __shared__ alignas(16) uint16_t lsV[2][128 * 32];
  __shared__ alignas(16) uint16_t pls[4][2][16 * 40];

  const uint16_t* qptr = qb  + ((size_t)bh * SS + qrow_w) * HD;
  const uint16_t* kg   = kb  + (size_t)bh * SS * HD;
  const uint16_t* vg   = vtb + (size_t)bh * (size_t)HD * SS;

  bf16x8 qf[2][4];
  #pragma unroll
  for (int m = 0; m < 2; ++m)
    #pragma unroll
    for (int c = 0; c < 4; ++c)
      qf[m][c] = *reinterpret_cast<const bf16x8*>(
          qptr + (size_t)(m * 16 + l15) * HD + c * 32 + lk * 8);

  floatx4 o[2][8];
  #pragma unroll
  for (int m = 0; m < 2; ++m)
    #pragma unroll
    for (int i = 0; i < 8; i++) o[m][i] = floatx4{0.f, 0.f, 0.f, 0.f};
  float m2[2][4], lsum[2][4];
  #pragma unroll
  for (int m = 0; m < 2; ++m)
    #pragma unroll
    for (int r = 0; r < 4; r++) { m2[m][r] = -__builtin_inff(); lsum[m][r] = 0.f; }

  // stage K (32x128) + V (128x32) for tile kt2 into LDS buffer bi.
  // 4 gload16 per thread. Linear LDS in lane order; chunk-XOR swizzle on
  // the GLOBAL source address.
  auto stage = [&](int bi, int kt2) {
    const int kb2 = kt2 * 32;
    #pragma unroll
    for (int j = 0; j < 2; ++j) {
      int g  = j * 256 + t;
      int kr = g >> 4, ks = g & 15;              // K: 32 rows x 16 chunks
      gload16(kg + (size_t)(kb2 + kr) * HD + ((ks ^ (kr & 7)) << 3), &lsK[bi][g * 8]);
      int vr = g >> 2, vs = g & 3;               // V: 128 rows x 4 chunks
      gload16(vg + (size_t)vr * SS + kb2 + ((vs ^ (vr & 3)) << 3), &lsV[bi][g * 8]);
    }
  };

  const int ktiles = qblk * 4 + 4;
  stage(0, 0);

  for (int kt = 0; kt < ktiles; ++kt) {
    const int cur   = kt & 1;
    const int kbase = kt * 32;

    // issue next tile's loads, then wait ONLY for the current tile's
    // (issued one full iteration ago) -> next tile's stay in flight.
    if (kt + 1 < ktiles) {
      stage(cur ^ 1, kt + 1);
      asm volatile("s_waitcnt vmcnt(4)" ::: "memory");
    } else {
      asm volatile("s_waitcnt vmcnt(0)" ::: "memory");
    }
    __builtin_amdgcn_s_barrier();   // all waves: current tile landed

    if (kbase <= qrow_w + 31) {
      // ---- QK^T: 16 MFMAs, K frags shared across m ----
      floatx4 sa[2], sb[2];
      sa[0] = floatx4{0.f,0.f,0.f,0.f}; sa[1] = floatx4{0.f,0.f,0.f,0.f};
      sb[0] = floatx4{0.f,0.f,0.f,0.f}; sb[1] = floatx4{0.f,0.f,0.f,0.f};
      #pragma unroll
      for (int c = 0; c < 4; ++c) {
        int kr0 = l15, kr1 = 16 + l15;
        bf16x8 k0 = *reinterpret_cast<const bf16x8*>(
            &lsK[cur][kr0 * 128 + (((c * 4 + lk) ^ (kr0 & 7)) * 8)]);
        bf16x8 k1 = *reinterpret_cast<const bf16x8*>(
            &lsK[cur][kr1 * 128 + (((c * 4 + lk) ^ (kr1 & 7)) * 8)]);
        sa[0] = mfma16(qf[0][c], k0, sa[0]);
        sb[0] = mfma16(qf[0][c], k1, sb[0]);
        sa[1] = mfma16(qf[1][c], k0, sa[1]);
        sb[1] = mfma16(qf[1][c], k1, sb[1]);
      }

      // ---- softmax for both m, P writes queued, ONE lgkm wait ----
      #pragma unroll
      for (int m = 0; m < 2; ++m) {
        const int qrm = qrow_w + m * 16;
        if (kbase + 31 > qrm) {  // diagonal tile: causal mask
          #pragma unroll
          for (int r = 0; r < 4; r++) {
            int qr = qrm + lk * 4 + r;
            if (kbase + l15 > qr)      sa[m][r] = -__builtin_inff();
            if (kbase + 16 + l15 > qr) sb[m][r] = -__builtin_inff();
          }
        }
        float alpha[4];
        #pragma unroll
        for (int r = 0; r < 4; r++) {
          float mt = fmaxf(sa[m][r], sb[m][r]);
          #pragma unroll
          for (int off = 1; off < 16; off <<= 1) mt = fmaxf(mt, __shfl_xor(mt, off));
          float mo = m2[m][r];
          float mn = (mt > mo + 8.f) ? mt : mo;   // defer-max
          alpha[r] = EXP2F(mo - mn);               // exactly 1.0 when deferred
          m2[m][r] = mn;
        }
        uint16_t* pbuf = pls[w][m];
        #pragma unroll
        for (int r = 0; r < 4; r++) {
          float p0 = EXP2F(sa[m][r] - m2[m][r]);
          float p1 = EXP2F(sb[m][r] - m2[m][r]);
          float ps = p0 + p1;
          #pragma unroll
          for (int off = 1; off < 16; off <<= 1) ps += __shfl_xor(ps, off);
          lsum[m][r] = lsum[m][r] * alpha[r] + ps;
          pbuf[(lk * 4 + r) * 40 + l15]      = f2bf(p0);
          pbuf[(lk * 4 + r) * 40 + 16 + l15] = f2bf(p1);
        }
        if (__any(alpha[0] != 1.f || alpha[1] != 1.f ||
                  alpha[2] != 1.f || alpha[3] != 1.f)) {
          #pragma unroll
          for (int i = 0; i < 8; i++)
            #pragma unroll
            for (int r = 0; r < 4; r++) o[m][i][r] *= alpha[r];
        }
      }

      // P: C-layout -> A-layout via LDS round trip (wave-private, lockstep)
      asm volatile("s_waitcnt lgkmcnt(0)" ::: "memory");
      bf16x8 pf0 = *reinterpret_cast<const bf16x8*>(pls[w][0] + l15 * 40 + lk * 8);
      bf16x8 pf1 = *reinterpret_cast<const bf16x8*>(pls[w][1] + l15 * 40 + lk * 8);

      // ---- PV: 16 MFMAs, V frags shared across m ----
      #pragma unroll
      for (int i = 0; i < 8; i++) {
        int vrr = i * 16 + l15;
        bf16x8 vf = *reinterpret_cast<const bf16x8*>(
            &lsV[cur][vrr * 32 + ((lk ^ (vrr & 3)) * 8)]);
        o[0][i] = mfma16(pf0, vf, o[0][i]);
        o[1][i] = mfma16(pf1, vf, o[1][i]);
      }
    }
    __builtin_amdgcn_s_barrier();   // all waves done reading buf before reuse
  }

  #pragma unroll
  for (int m = 0; m < 2; ++m) {
    float inv[4];
    #pragma unroll
    for (int r = 0; r < 4; r++) inv[r] = 1.0f / lsum[m][r];
    uint16_t* cdst = ctxb + ((size_t)b * SS + qrow_w + m * 16) * HIDD + h * HD;
    #pragma unroll
    for (int i = 0; i < 8; i++)
      #pragma unroll
      for (int r = 0; r < 4; r++)
        cdst[(size_t)(lk * 4 + r) * HIDD + i * 16 + l15] = f2bf(o[m][i][r] * inv[r]);
  }
}

// ---------------- launch ----------------
extern "C" void kernel_launch(void* const* d_in, const int* in_sizes, int n_in,
                              void* d_out, int out_size, void* d_ws, size_t ws_size,
                              hipStream_t stream) {
  const float* x  = (const float*)d_in[0];
  const float* Wq = (const float*)d_in[1];
  const float* Wk = (const float*)d_in[2];
  const float* Wv = (const float*)d_in[3];
  const float* Wo = (const float*)d_in[4];
  float* out = (float*)d_out;
  float* kv  = out + (size_t)BB * SS * HIDD;  // kv cache region

  uint8_t* ws = (uint8_t*)d_ws;
  // byte offsets (total 160 MiB)
  uint16_t* xb  = (uint16_t*)(ws);              // 32 MiB; reused as ctx after attn
  uint16_t* qb  = (uint16_t*)(ws + 33554432);
  uint16_t* kb  = (uint16_t*)(ws + 67108864);
  uint16_t* vtb = (uint16_t*)(ws + 100663296);
  uint16_t* wqb = (uint16_t*)(ws + 134217728);
  uint16_t* wkb = (uint16_t*)(ws + 142606336);
  uint16_t* wvb = (uint16_t*)(ws + 150994944);
  uint16_t* wob = (uint16_t*)(ws + 159383552);

  const float QSCALE = 0.08838834764831845f * 1.4426950408889634f; // D^-0.5 * log2(e)

  cvt_f32_bf16<<<16384, 256, 0, stream>>>(x,  xb);
  cvt_f32_bf16<<<4096,  256, 0, stream>>>(Wq, wqb);
  cvt_f32_bf16<<<4096,  256, 0, stream>>>(Wk, wkb);
  cvt_f32_bf16<<<4096,  256, 0, stream>>>(Wv, wvb);
  cvt_f32_bf16<<<4096,  256, 0, stream>>>(Wo, wob);

  dim3 ggrid(HIDD / 128, (BB * SS) / 128);  // (16, 64)
  gemm_bf16<<<ggrid, 256, 0, stream>>>(xb, wqb, qb,  nullptr, 0, QSCALE);
  gemm_bf16<<<ggrid, 256, 0, stream>>>(xb, wkb, kb,  kv,      1, 1.0f);
  gemm_bf16<<<ggrid, 256, 0, stream>>>(xb, wvb, vtb, kv,      2, 1.0f);

  attn_fwd<<<dim3(1024), 256, 0, stream>>>(qb, kb, vtb, xb /*ctx*/);

  gemm_bf16<<<ggrid, 256, 0, stream>>>(xb, wob, nullptr, out, 3, 1.0f);
}

// Round 4
// 887.315 us; speedup vs baseline: 1.8257x; 1.2598x over previous
//
#include <hip/hip_runtime.h>
#include <stdint.h>

// Problem constants
#define BB   4
#define SS   2048
#define HIDD 2048
#define NH   16
#define HD   128

#define QSCALE_F (0.08838834764831845f * 1.4426950408889634f)  // D^-0.5 * log2(e)

typedef float  floatx4 __attribute__((ext_vector_type(4)));
typedef __bf16 bf16x8  __attribute__((ext_vector_type(8)));
typedef unsigned short ushort8  __attribute__((ext_vector_type(8)));
typedef unsigned short ushort4v __attribute__((ext_vector_type(4)));

__device__ __forceinline__ uint16_t f2bf(float f) {
  uint32_t u = __builtin_bit_cast(uint32_t, f);
  u += 0x7FFFu + ((u >> 16) & 1u);   // RNE
  return (uint16_t)(u >> 16);
}

// pack 2 f32 -> 2 bf16 in one u32 (RNE), T12 recipe
__device__ __forceinline__ uint32_t cvtpk(float lo, float hi) {
  uint32_t r;
  asm("v_cvt_pk_bf16_f32 %0, %1, %2" : "=v"(r) : "v"(lo), "v"(hi));
  return r;
}

__device__ __forceinline__ floatx4 mfma16(bf16x8 a, bf16x8 b, floatx4 c) {
  return __builtin_amdgcn_mfma_f32_16x16x32_bf16(a, b, c, 0, 0, 0);
}

// async global->LDS, 16B per lane. LDS dest must be wave-uniform base + lane*16.
__device__ __forceinline__ void gload16(const void* g, void* l) {
  __builtin_amdgcn_global_load_lds(
      (__attribute__((address_space(1))) void*)g,
      (__attribute__((address_space(3))) void*)l, 16, 0, 0);
}

#if __has_builtin(__builtin_amdgcn_exp2f)
#define EXP2F(x) __builtin_amdgcn_exp2f(x)
#else
#define EXP2F(x) exp2f(x)
#endif

// ---------------- fp32 -> bf16 convert (vector x4) ----------------
__global__ void cvt_f32_bf16(const float* __restrict__ src, uint16_t* __restrict__ dst) {
  int idx = (blockIdx.x * 256 + threadIdx.x) * 4;
  const float4 v = *reinterpret_cast<const float4*>(src + idx);
  ushort4v o = { f2bf(v.x), f2bf(v.y), f2bf(v.z), f2bf(v.w) };
  *reinterpret_cast<ushort4v*>(dst + idx) = o;
}

// 4 weight matrices (separate srcs) -> one contiguous bf16 region
__global__ void cvt_w4(const float* __restrict__ s0, const float* __restrict__ s1,
                       const float* __restrict__ s2, const float* __restrict__ s3,
                       uint16_t* __restrict__ dst) {
  int bi = blockIdx.x >> 12;               // 4096 blocks per weight
  const float* src = bi == 0 ? s0 : bi == 1 ? s1 : bi == 2 ? s2 : s3;
  int idx = ((blockIdx.x & 4095) * 256 + threadIdx.x) * 4;
  const float4 v = *reinterpret_cast<const float4*>(src + idx);
  ushort4v o = { f2bf(v.x), f2bf(v.y), f2bf(v.z), f2bf(v.w) };
  *reinterpret_cast<ushort4v*>(dst + (size_t)bi * 4194304 + idx) = o;
}

// ---------------- bf16 GEMM: C[M,N] = A[M,K] * W[N,K]^T ----------------
// 128x128 block tile, 4 waves 2x2, wave 64x64 via 4x4 MFMA tiles.
// Flat 1-D grid, XCD-clustered decode (id&7 = xcd):
//   mode 4 (fused QKV): 3072 blocks, 48 cols; each XCD owns 6 cols (3MB B
//     panel L2-resident), A row-block reused by 6 consecutive blocks.
//     md = bx>>4 selects Q/K/V epilogue; Q scaled by QSCALE.
//   mode 3 (Wo): 1024 blocks, 16 cols; each XCD owns 2 cols. fp32 out.
// LDS: elem (row,k) at row*32 + ((kc ^ ((row>>1)&3))*8 + (k&7)); staged via
// global_load_lds w16 (LDS linear in lane order, swizzle on global src).
__global__ __launch_bounds__(256) void gemm_bf16(
    const uint16_t* __restrict__ A,
    const uint16_t* __restrict__ Bw,
    uint16_t* __restrict__ oQ,
    uint16_t* __restrict__ oK,
    uint16_t* __restrict__ oV,
    float* __restrict__ outf,
    int mode)
{
  __shared__ alignas(16) uint16_t lsA[128 * 32];
  __shared__ alignas(16) uint16_t lsB[128 * 32];

  const int t    = threadIdx.x;
  const int lane = t & 63;
  const int wv   = t >> 6;
  const int wx   = wv & 1;
  const int wy   = wv >> 1;
  const int l15  = lane & 15;
  const int lk   = lane >> 4;

  const int id = blockIdx.x;
  int bx, by;
  if (mode == 4) { int lin = id >> 3; bx = (id & 7) * 6 + lin % 6; by = lin / 6; }
  else           { int lin = id >> 3; bx = (id & 7) * 2 + (lin & 1); by = lin >> 1; }
  const int m0 = by * 128;
  const int n0 = bx * 128;

  const int srow = t >> 2;                     // staging row (0..63), +64 on 2nd chunk
  const int skc  = t & 3;                      // staging k-slot (LDS position)
  const int kc   = skc ^ ((srow >> 1) & 3);    // pre-swizzled global k-chunk

  floatx4 acc[4][4];
  #pragma unroll
  for (int i = 0; i < 4; i++)
    #pragma unroll
    for (int j = 0; j < 4; j++) acc[i][j] = floatx4{0.f, 0.f, 0.f, 0.f};

  const uint16_t* Ag = A  + (size_t)m0 * HIDD;
  const uint16_t* Bg = Bw + (size_t)n0 * HIDD;

  for (int k0 = 0; k0 < HIDD; k0 += 32) {
    #pragma unroll
    for (int i = 0; i < 2; ++i) {
      int row = srow + i * 64;
      gload16(Ag + (size_t)row * HIDD + k0 + kc * 8, &lsA[row * 32 + skc * 8]);
      gload16(Bg + (size_t)row * HIDD + k0 + kc * 8, &lsB[row * 32 + skc * 8]);
    }
    __syncthreads();

    bf16x8 af[4], bf[4];
    #pragma unroll
    for (int mi = 0; mi < 4; mi++) {
      int row = wy * 64 + mi * 16 + l15;
      af[mi] = *reinterpret_cast<const bf16x8*>(&lsA[row * 32 + ((lk ^ ((row >> 1) & 3)) << 3)]);
    }
    #pragma unroll
    for (int nj = 0; nj < 4; nj++) {
      int row = wx * 64 + nj * 16 + l15;
      bf[nj] = *reinterpret_cast<const bf16x8*>(&lsB[row * 32 + ((lk ^ ((row >> 1) & 3)) << 3)]);
    }
    #pragma unroll
    for (int mi = 0; mi < 4; mi++)
      #pragma unroll
      for (int nj = 0; nj < 4; nj++)
        acc[mi][nj] = mfma16(af[mi], bf[nj], acc[mi][nj]);
    __syncthreads();
  }

  // Epilogue. C layout: col = lane&15, row = (lane>>4)*4 + reg  [verified m89/m91]
  const int md = (mode == 4) ? (bx >> 4) : 3;   // 0 Q, 1 K, 2 V, 3 Wo
  const float scl = (md == 0) ? QSCALE_F : 1.0f;
  #pragma unroll
  for (int mi = 0; mi < 4; mi++) {
    int rbase = m0 + wy * 64 + mi * 16 + lk * 4;
    #pragma unroll
    for (int nj = 0; nj < 4; nj++) {
      int col = n0 + wx * 64 + nj * 16 + l15;
      floatx4 v = acc[mi][nj];
      #pragma unroll
      for (int r = 0; r < 4; r++) {
        int rr = rbase + r;
        float val = v[r] * scl;
        int b_ = rr >> 11, s_ = rr & 2047;
        if (md == 3) {
          outf[(size_t)rr * HIDD + col] = val;
        } else {
          int coll = col & 2047;
          int h_ = coll >> 7, d_ = coll & 127;
          size_t bh = (size_t)(b_ * NH + h_);
          if (md == 0) {
            oQ[(bh * SS + s_) * HD + d_] = f2bf(val);
          } else if (md == 1) {
            oK[(bh * SS + s_) * HD + d_] = f2bf(val);
            outf[((bh * 2 + 0) * SS + s_) * HD + d_] = val;
          } else {
            oV[(bh * HD + d_) * SS + s_] = f2bf(val);
            outf[((bh * 2 + 1) * SS + s_) * HD + d_] = val;
          }
        }
      }
    }
  }
}

// ---------------- causal flash attention v5: swapped QK^T ----------------
// Flat 1024 blocks (xcd=id&7 cluster, qblk heavy-first), 256 thr = 4 waves,
// wave w owns q rows qblk*128+w*32..+31 as two 16-row tiles (m=0,1).
// SWAPPED QK^T: S^T = mfma(K_frag, Q_frag) -> lane (l15,lk) holds 8 scores of
// q = l15: k = kbase + {lk*4+r, 16+lk*4+r}. Softmax state (m2,lsum,alpha) is
// lane-local; row-reduce = in-reg tree + shfl_xor(16,32) only.
// P^T repack: cvt_pk -> 2x ds_write_b64; PV B-frag = 1x ds_read_b128 (natural
// layout). PV computed as O^T = V^T * P^T: A = V^T frags (existing lsV reads),
// output col = l15 = q matches lane-local alpha. No cross-lane redistribution.
// K/V double-buffered via global_load_lds, counted vmcnt(4), raw barriers.
__global__ __launch_bounds__(256) void attn_fwd(
    const uint16_t* __restrict__ qb,
    const uint16_t* __restrict__ kb,
    const uint16_t* __restrict__ vtb,
    uint16_t* __restrict__ ctxb)
{
  const int id   = blockIdx.x;
  const int xcd  = id & 7;
  const int kk   = id >> 3;
  const int ybh  = kk >> 4;
  const int qblk = 15 - (kk & 15);        // heavy-first
  const int bh   = (ybh << 3) | xcd;      // XCD-clustered bh
  const int b    = bh >> 4;
  const int h    = bh & 15;
  const int t    = threadIdx.x;
  const int lane = t & 63;
  const int w    = t >> 6;
  const int l15  = lane & 15;
  const int lk   = lane >> 4;

  const int qrow_w = qblk * 128 + w * 32;

  // LDS: 2x K 8KB + 2x V 8KB + P 12KB = 44KB (3 blocks/CU).
  __shared__ alignas(16) uint16_t lsK[2][32 * 128];
  __shared__ alignas(16) uint16_t lsV[2][128 * 32];
  __shared__ alignas(16) uint16_t pls[4][2][16 * 48];  // stride 48 elems = 96B (16B-aligned rows)

  const uint16_t* qptr = qb  + ((size_t)bh * SS + qrow_w) * HD;
  const uint16_t* kg   = kb  + (size_t)bh * SS * HD;
  const uint16_t* vg   = vtb + (size_t)bh * (size_t)HD * SS;

  // Q fragment: works as B-operand (col = q = l15, k = c*32 + lk*8 + j)
  bf16x8 qf[2][4];
  #pragma unroll
  for (int m = 0; m < 2; ++m)
    #pragma unroll
    for (int c = 0; c < 4; ++c)
      qf[m][c] = *reinterpret_cast<const bf16x8*>(
          qptr + (size_t)(m * 16 + l15) * HD + c * 32 + lk * 8);

  // O^T accumulator: o[m][i][r] = O[q = qrow_w+m*16+l15][d = i*16 + lk*4 + r]
  floatx4 o[2][8];
  #pragma unroll
  for (int m = 0; m < 2; ++m)
    #pragma unroll
    for (int i = 0; i < 8; i++) o[m][i] = floatx4{0.f, 0.f, 0.f, 0.f};
  float m2[2], lsum[2];
  m2[0] = m2[1] = -__builtin_inff();
  lsum[0] = lsum[1] = 0.f;

  auto stage = [&](int bi, int kt2) {
    const int kb2 = kt2 * 32;
    #pragma unroll
    for (int j = 0; j < 2; ++j) {
      int g  = j * 256 + t;
      int kr = g >> 4, ks = g & 15;              // K: 32 rows x 16 chunks
      gload16(kg + (size_t)(kb2 + kr) * HD + ((ks ^ (kr & 7)) << 3), &lsK[bi][g * 8]);
      int vr = g >> 2, vs = g & 3;               // V: 128 rows x 4 chunks
      gload16(vg + (size_t)vr * SS + kb2 + ((vs ^ (vr & 3)) << 3), &lsV[bi][g * 8]);
    }
  };

  const int ktiles = qblk * 4 + 4;
  stage(0, 0);

  const int e7 = l15 & 7;   // K-frag row-XOR (rows l15 and 16+l15 share low 3 bits)

  for (int kt = 0; kt < ktiles; ++kt) {
    const int cur   = kt & 1;
    const int kbase = kt * 32;

    if (kt + 1 < ktiles) {
      stage(cur ^ 1, kt + 1);
      asm volatile("s_waitcnt vmcnt(4)" ::: "memory");
    } else {
      asm volatile("s_waitcnt vmcnt(0)" ::: "memory");
    }
    __builtin_amdgcn_s_barrier();   // current tile landed

    if (kbase <= qrow_w + 31) {
      // ---- swapped QK^T: S^T[k][q], 16 MFMAs ----
      floatx4 sa[2], sb[2];
      sa[0] = floatx4{0.f,0.f,0.f,0.f}; sa[1] = floatx4{0.f,0.f,0.f,0.f};
      sb[0] = floatx4{0.f,0.f,0.f,0.f}; sb[1] = floatx4{0.f,0.f,0.f,0.f};
      #pragma unroll
      for (int c = 0; c < 4; ++c) {
        bf16x8 k0 = *reinterpret_cast<const bf16x8*>(
            &lsK[cur][l15 * 128 + (((c * 4 + lk) ^ e7) * 8)]);
        bf16x8 k1 = *reinterpret_cast<const bf16x8*>(
            &lsK[cur][(16 + l15) * 128 + (((c * 4 + lk) ^ e7) * 8)]);
        sa[0] = mfma16(k0, qf[0][c], sa[0]);
        sa[1] = mfma16(k0, qf[1][c], sa[1]);
        sb[0] = mfma16(k1, qf[0][c], sb[0]);
        sb[1] = mfma16(k1, qf[1][c], sb[1]);
      }

      // ---- lane-local softmax (q = l15 within each m-tile) ----
      float alpha[2];
      #pragma unroll
      for (int m = 0; m < 2; ++m) {
        const int qrm = qrow_w + m * 16;
        const int q   = qrm + l15;
        if (kbase + 31 > qrm) {   // diagonal tile: causal mask (k > q -> -inf)
          #pragma unroll
          for (int r = 0; r < 4; r++) {
            if (kbase + lk * 4 + r > q)      sa[m][r] = -__builtin_inff();
            if (kbase + 16 + lk * 4 + r > q) sb[m][r] = -__builtin_inff();
          }
        }
        float mt = fmaxf(fmaxf(fmaxf(sa[m][0], sa[m][1]), fmaxf(sa[m][2], sa[m][3])),
                         fmaxf(fmaxf(sb[m][0], sb[m][1]), fmaxf(sb[m][2], sb[m][3])));
        mt = fmaxf(mt, __shfl_xor(mt, 16));
        mt = fmaxf(mt, __shfl_xor(mt, 32));
        float mo = m2[m];
        float mn = (mt > mo + 8.f) ? mt : mo;   // defer-max (T13)
        alpha[m] = EXP2F(mo - mn);               // exactly 1.0 when deferred
        m2[m] = mn;
        #pragma unroll
        for (int r = 0; r < 4; r++) {
          sa[m][r] = EXP2F(sa[m][r] - mn);
          sb[m][r] = EXP2F(sb[m][r] - mn);
        }
        float ps = ((sa[m][0] + sa[m][1]) + (sa[m][2] + sa[m][3]))
                 + ((sb[m][0] + sb[m][1]) + (sb[m][2] + sb[m][3]));
        ps += __shfl_xor(ps, 16);
        ps += __shfl_xor(ps, 32);
        lsum[m] = lsum[m] * alpha[m] + ps;

        // P^T pack & stash: row q=l15, cols {lk*4.., 16+lk*4..}
        uint16_t* pbuf = pls[w][m];
        uint2 w01 = { cvtpk(sa[m][0], sa[m][1]), cvtpk(sa[m][2], sa[m][3]) };
        uint2 w23 = { cvtpk(sb[m][0], sb[m][1]), cvtpk(sb[m][2], sb[m][3]) };
        *reinterpret_cast<uint2*>(&pbuf[l15 * 48 + lk * 4])      = w01;
        *reinterpret_cast<uint2*>(&pbuf[l15 * 48 + 16 + lk * 4]) = w23;
      }

      if (__any(alpha[0] != 1.f || alpha[1] != 1.f)) {
        #pragma unroll
        for (int m = 0; m < 2; ++m)
          #pragma unroll
          for (int i = 0; i < 8; i++)
            #pragma unroll
            for (int r = 0; r < 4; r++) o[m][i][r] *= alpha[m];
      }

      // P^T B-frag: col q = l15, k = s = lk*8+j  (contiguous row read)
      asm volatile("s_waitcnt lgkmcnt(0)" ::: "memory");
      bf16x8 pf0 = *reinterpret_cast<const bf16x8*>(&pls[w][0][l15 * 48 + lk * 8]);
      bf16x8 pf1 = *reinterpret_cast<const bf16x8*>(&pls[w][1][l15 * 48 + lk * 8]);

      // ---- PV as O^T = V^T * P^T: 16 MFMAs, V frags shared across m ----
      #pragma unroll
      for (int i = 0; i < 8; i++) {
        int vrr = i * 16 + l15;
        bf16x8 vf = *reinterpret_cast<const bf16x8*>(
            &lsV[cur][vrr * 32 + ((lk ^ (vrr & 3)) * 8)]);
        o[0][i] = mfma16(vf, pf0, o[0][i]);
        o[1][i] = mfma16(vf, pf1, o[1][i]);
      }
    }
    __builtin_amdgcn_s_barrier();   // all waves done with buf before reuse
  }

  // epilogue: O[q = qrow_w+m*16+l15][d = i*16+lk*4+r], packed 8B stores
  #pragma unroll
  for (int m = 0; m < 2; ++m) {
    float inv = 1.0f / lsum[m];
    uint16_t* base = ctxb + ((size_t)b * SS + qrow_w + m * 16 + l15) * HIDD
                   + h * HD + lk * 4;
    #pragma unroll
    for (int i = 0; i < 8; i++) {
      uint2 pr = { cvtpk(o[m][i][0] * inv, o[m][i][1] * inv),
                   cvtpk(o[m][i][2] * inv, o[m][i][3] * inv) };
      *reinterpret_cast<uint2*>(base + i * 16) = pr;
    }
  }
}

// ---------------- launch ----------------
extern "C" void kernel_launch(void* const* d_in, const int* in_sizes, int n_in,
                              void* d_out, int out_size, void* d_ws, size_t ws_size,
                              hipStream_t stream) {
  const float* x  = (const float*)d_in[0];
  const float* Wq = (const float*)d_in[1];
  const float* Wk = (const float*)d_in[2];
  const float* Wv = (const float*)d_in[3];
  const float* Wo = (const float*)d_in[4];
  float* out = (float*)d_out;
  float* kv  = out + (size_t)BB * SS * HIDD;  // kv cache region

  uint8_t* ws = (uint8_t*)d_ws;
  // byte offsets (total 160 MiB)
  uint16_t* xb  = (uint16_t*)(ws);              // 32 MiB; reused as ctx after attn
  uint16_t* qb  = (uint16_t*)(ws + 33554432);
  uint16_t* kb  = (uint16_t*)(ws + 67108864);
  uint16_t* vtb = (uint16_t*)(ws + 100663296);
  uint16_t* wqb = (uint16_t*)(ws + 134217728);  // wq,wk,wv,wo contiguous (4x8MB)
  uint16_t* wob = (uint16_t*)(ws + 159383552);

  cvt_f32_bf16<<<16384, 256, 0, stream>>>(x, xb);
  cvt_w4<<<16384, 256, 0, stream>>>(Wq, Wk, Wv, Wo, wqb);

  // fused QKV projection (mode 4): 48 col-blocks x 64 row-blocks
  gemm_bf16<<<3072, 256, 0, stream>>>(xb, wqb, qb, kb, vtb, kv, 4);

  attn_fwd<<<1024, 256, 0, stream>>>(qb, kb, vtb, xb /*ctx*/);

  // output projection (mode 3)
  gemm_bf16<<<1024, 256, 0, stream>>>(xb, wob, nullptr, nullptr, nullptr, out, 3);
}

// Round 5
// 885.254 us; speedup vs baseline: 1.8300x; 1.0023x over previous
//
#include <hip/hip_runtime.h>
#include <stdint.h>

// Problem constants
#define BB   4
#define SS   2048
#define HIDD 2048
#define NH   16
#define HD   128

#define QSCALE_F (0.08838834764831845f * 1.4426950408889634f)  // D^-0.5 * log2(e)

typedef float  floatx4 __attribute__((ext_vector_type(4)));
typedef __bf16 bf16x8  __attribute__((ext_vector_type(8)));
typedef unsigned short ushort8  __attribute__((ext_vector_type(8)));
typedef unsigned short ushort4v __attribute__((ext_vector_type(4)));

__device__ __forceinline__ uint16_t f2bf(float f) {
  uint32_t u = __builtin_bit_cast(uint32_t, f);
  u += 0x7FFFu + ((u >> 16) & 1u);   // RNE
  return (uint16_t)(u >> 16);
}

// pack 2 f32 -> 2 bf16 in one u32 (RNE), T12 recipe
__device__ __forceinline__ uint32_t cvtpk(float lo, float hi) {
  uint32_t r;
  asm("v_cvt_pk_bf16_f32 %0, %1, %2" : "=v"(r) : "v"(lo), "v"(hi));
  return r;
}

__device__ __forceinline__ floatx4 mfma16(bf16x8 a, bf16x8 b, floatx4 c) {
  return __builtin_amdgcn_mfma_f32_16x16x32_bf16(a, b, c, 0, 0, 0);
}

// async global->LDS, 16B per lane. LDS dest must be wave-uniform base + lane*16.
__device__ __forceinline__ void gload16(const void* g, void* l) {
  __builtin_amdgcn_global_load_lds(
      (__attribute__((address_space(1))) void*)g,
      (__attribute__((address_space(3))) void*)l, 16, 0, 0);
}

#if __has_builtin(__builtin_amdgcn_exp2f)
#define EXP2F(x) __builtin_amdgcn_exp2f(x)
#else
#define EXP2F(x) exp2f(x)
#endif

// ---------------- fp32 -> bf16 convert (vector x4) ----------------
__global__ void cvt_f32_bf16(const float* __restrict__ src, uint16_t* __restrict__ dst) {
  int idx = (blockIdx.x * 256 + threadIdx.x) * 4;
  const float4 v = *reinterpret_cast<const float4*>(src + idx);
  ushort4v o = { f2bf(v.x), f2bf(v.y), f2bf(v.z), f2bf(v.w) };
  *reinterpret_cast<ushort4v*>(dst + idx) = o;
}

// 4 weight matrices (separate srcs) -> one contiguous bf16 region
__global__ void cvt_w4(const float* __restrict__ s0, const float* __restrict__ s1,
                       const float* __restrict__ s2, const float* __restrict__ s3,
                       uint16_t* __restrict__ dst) {
  int bi = blockIdx.x >> 12;               // 4096 blocks per weight
  const float* src = bi == 0 ? s0 : bi == 1 ? s1 : bi == 2 ? s2 : s3;
  int idx = ((blockIdx.x & 4095) * 256 + threadIdx.x) * 4;
  const float4 v = *reinterpret_cast<const float4*>(src + idx);
  ushort4v o = { f2bf(v.x), f2bf(v.y), f2bf(v.z), f2bf(v.w) };
  *reinterpret_cast<ushort4v*>(dst + (size_t)bi * 4194304 + idx) = o;
}

// ---------------- bf16 GEMM: C[M,N] = A[M,K] * W[N,K]^T ----------------
// 128x128 block tile, 4 waves 2x2, wave 64x64 via 4x4 MFMA tiles.
// Flat 1-D grid, XCD-clustered decode (id&7 = xcd):
//   mode 4 (fused QKV): 3072 blocks, 48 cols; each XCD owns 6 cols (3MB B
//     panel L2-resident). md = bx>>4 selects Q/K/V epilogue; Q scaled.
//   mode 3 (Wo): 1024 blocks, 16 cols; each XCD owns 2 cols. fp32 out.
// Mainloop LDS: elem (row,k) at row*32 + ((kc ^ ((row>>1)&3))*8 + (k&7));
// staged via global_load_lds w16 (LDS linear, swizzle on global src).
// V epilogue: bf16 V^T store goes through an LDS transpose (two 64-col
// halves, 64x136 padded) -> 256B-contiguous dwordx4 global stores, instead
// of 64-way-scattered 2B stores (was ~half the kernel's time).
__global__ __launch_bounds__(256) void gemm_bf16(
    const uint16_t* __restrict__ A,
    const uint16_t* __restrict__ Bw,
    uint16_t* __restrict__ oQ,
    uint16_t* __restrict__ oK,
    uint16_t* __restrict__ oV,
    float* __restrict__ outf,
    int mode)
{
  // union: mainloop lsA = smem[0:4096], lsB = smem[4096:8192] (128x32 each);
  // V^T transpose half-tile: 64 x 136 elems = 8704 (17.4KB total)
  __shared__ alignas(16) uint16_t smem[8704];
  uint16_t* lsA = smem;
  uint16_t* lsB = smem + 4096;

  const int t    = threadIdx.x;
  const int lane = t & 63;
  const int wv   = t >> 6;
  const int wx   = wv & 1;
  const int wy   = wv >> 1;
  const int l15  = lane & 15;
  const int lk   = lane >> 4;

  const int id = blockIdx.x;
  int bx, by;
  if (mode == 4) { int lin = id >> 3; bx = (id & 7) * 6 + lin % 6; by = lin / 6; }
  else           { int lin = id >> 3; bx = (id & 7) * 2 + (lin & 1); by = lin >> 1; }
  const int m0 = by * 128;
  const int n0 = bx * 128;

  const int srow = t >> 2;                     // staging row (0..63), +64 on 2nd chunk
  const int skc  = t & 3;                      // staging k-slot (LDS position)
  const int kc   = skc ^ ((srow >> 1) & 3);    // pre-swizzled global k-chunk

  floatx4 acc[4][4];
  #pragma unroll
  for (int i = 0; i < 4; i++)
    #pragma unroll
    for (int j = 0; j < 4; j++) acc[i][j] = floatx4{0.f, 0.f, 0.f, 0.f};

  const uint16_t* Ag = A  + (size_t)m0 * HIDD;
  const uint16_t* Bg = Bw + (size_t)n0 * HIDD;

  for (int k0 = 0; k0 < HIDD; k0 += 32) {
    #pragma unroll
    for (int i = 0; i < 2; ++i) {
      int row = srow + i * 64;
      gload16(Ag + (size_t)row * HIDD + k0 + kc * 8, &lsA[row * 32 + skc * 8]);
      gload16(Bg + (size_t)row * HIDD + k0 + kc * 8, &lsB[row * 32 + skc * 8]);
    }
    __syncthreads();

    bf16x8 af[4], bf[4];
    #pragma unroll
    for (int mi = 0; mi < 4; mi++) {
      int row = wy * 64 + mi * 16 + l15;
      af[mi] = *reinterpret_cast<const bf16x8*>(&lsA[row * 32 + ((lk ^ ((row >> 1) & 3)) << 3)]);
    }
    #pragma unroll
    for (int nj = 0; nj < 4; nj++) {
      int row = wx * 64 + nj * 16 + l15;
      bf[nj] = *reinterpret_cast<const bf16x8*>(&lsB[row * 32 + ((lk ^ ((row >> 1) & 3)) << 3)]);
    }
    #pragma unroll
    for (int mi = 0; mi < 4; mi++)
      #pragma unroll
      for (int nj = 0; nj < 4; nj++)
        acc[mi][nj] = mfma16(af[mi], bf[nj], acc[mi][nj]);
    __syncthreads();
  }

  // Epilogue. C layout: col = lane&15, row = (lane>>4)*4 + reg  [verified m89/m91]
  const int md = (mode == 4) ? (bx >> 4) : 3;   // 0 Q, 1 K, 2 V, 3 Wo
  if (md != 2) {
    const float scl = (md == 0) ? QSCALE_F : 1.0f;
    #pragma unroll
    for (int mi = 0; mi < 4; mi++) {
      int rbase = m0 + wy * 64 + mi * 16 + lk * 4;
      #pragma unroll
      for (int nj = 0; nj < 4; nj++) {
        int col = n0 + wx * 64 + nj * 16 + l15;
        floatx4 v = acc[mi][nj];
        #pragma unroll
        for (int r = 0; r < 4; r++) {
          int rr = rbase + r;
          float val = v[r] * scl;
          int b_ = rr >> 11, s_ = rr & 2047;
          if (md == 3) {
            outf[(size_t)rr * HIDD + col] = val;
          } else {
            int coll = col & 2047;
            int h_ = coll >> 7, d_ = coll & 127;
            size_t bh = (size_t)(b_ * NH + h_);
            if (md == 0) {
              oQ[(bh * SS + s_) * HD + d_] = f2bf(val);
            } else {
              oK[(bh * SS + s_) * HD + d_] = f2bf(val);
              outf[((bh * 2 + 0) * SS + s_) * HD + d_] = val;
            }
          }
        }
      }
    }
  } else {
    // ---- V: fp32 cache store (natural layout, semi-coalesced) ----
    const int b_  = m0 >> 11;
    const int s0g = m0 & 2047;
    const int h_  = bx & 15;
    const size_t bh = (size_t)(b_ * NH + h_);
    #pragma unroll
    for (int mi = 0; mi < 4; mi++) {
      int sbase = s0g + wy * 64 + mi * 16 + lk * 4;
      #pragma unroll
      for (int nj = 0; nj < 4; nj++) {
        int d_ = wx * 64 + nj * 16 + l15;
        floatx4 v = acc[mi][nj];
        #pragma unroll
        for (int r = 0; r < 4; r++)
          outf[((bh * 2 + 1) * SS + (sbase + r)) * HD + d_] = v[r];
      }
    }
    // ---- bf16 V^T store via LDS transpose (two 64-col halves) ----
    #pragma unroll
    for (int hh = 0; hh < 2; ++hh) {
      __syncthreads();   // previous half's reads / mainloop done
      if (wx == hh) {
        #pragma unroll
        for (int nj = 0; nj < 4; nj++) {
          int dl = nj * 16 + l15;
          #pragma unroll
          for (int mi = 0; mi < 4; mi++) {
            int s = wy * 64 + mi * 16 + lk * 4;
            floatx4 v = acc[mi][nj];
            uint2 pk = { cvtpk(v[0], v[1]), cvtpk(v[2], v[3]) };
            *reinterpret_cast<uint2*>(&smem[dl * 136 + s]) = pk;
          }
        }
      }
      __syncthreads();   // half-tile transposed in LDS
      #pragma unroll
      for (int it = 0; it < 4; ++it) {
        int dl = wv * 16 + it * 4 + lk;   // 4 d-rows per wave-read
        uint4 vv = *reinterpret_cast<const uint4*>(&smem[dl * 136 + l15 * 8]);
        *reinterpret_cast<uint4*>(
            oV + (bh * HD + hh * 64 + dl) * SS + s0g + l15 * 8) = vv;
      }
    }
  }
}

// ---------------- causal flash attention v5: swapped QK^T ----------------
// Flat 1024 blocks (xcd=id&7 cluster, qblk heavy-first), 256 thr = 4 waves,
// wave w owns q rows qblk*128+w*32..+31 as two 16-row tiles (m=0,1).
// SWAPPED QK^T: S^T = mfma(K_frag, Q_frag) -> lane (l15,lk) holds 8 scores of
// q = l15: k = kbase + {lk*4+r, 16+lk*4+r}. Softmax state lane-local;
// row-reduce = in-reg tree + shfl_xor(16,32) only.
// P^T repack: cvt_pk -> ds_write_b64 x2; PV B-frag = ds_read_b128 (natural).
// PV as O^T = V^T * P^T. K/V double-buffered via global_load_lds, counted
// vmcnt(4), raw barriers. T5 setprio around MFMA clusters.
__global__ __launch_bounds__(256) void attn_fwd(
    const uint16_t* __restrict__ qb,
    const uint16_t* __restrict__ kb,
    const uint16_t* __restrict__ vtb,
    uint16_t* __restrict__ ctxb)
{
  const int id   = blockIdx.x;
  const int xcd  = id & 7;
  const int kk   = id >> 3;
  const int ybh  = kk >> 4;
  const int qblk = 15 - (kk & 15);        // heavy-first
  const int bh   = (ybh << 3) | xcd;      // XCD-clustered bh
  const int b    = bh >> 4;
  const int h    = bh & 15;
  const int t    = threadIdx.x;
  const int lane = t & 63;
  const int w    = t >> 6;
  const int l15  = lane & 15;
  const int lk   = lane >> 4;

  const int qrow_w = qblk * 128 + w * 32;

  // LDS: 2x K 8KB + 2x V 8KB + P 12KB = 44KB (3 blocks/CU).
  __shared__ alignas(16) uint16_t lsK[2][32 * 128];
  __shared__ alignas(16) uint16_t lsV[2][128 * 32];
  __shared__ alignas(16) uint16_t pls[4][2][16 * 48];  // stride 48 elems

  const uint16_t* qptr = qb  + ((size_t)bh * SS + qrow_w) * HD;
  const uint16_t* kg   = kb  + (size_t)bh * SS * HD;
  const uint16_t* vg   = vtb + (size_t)bh * (size_t)HD * SS;

  // Q fragment: B-operand (col = q = l15, k = c*32 + lk*8 + j)
  bf16x8 qf[2][4];
  #pragma unroll
  for (int m = 0; m < 2; ++m)
    #pragma unroll
    for (int c = 0; c < 4; ++c)
      qf[m][c] = *reinterpret_cast<const bf16x8*>(
          qptr + (size_t)(m * 16 + l15) * HD + c * 32 + lk * 8);

  // O^T accumulator: o[m][i][r] = O[q = qrow_w+m*16+l15][d = i*16 + lk*4 + r]
  floatx4 o[2][8];
  #pragma unroll
  for (int m = 0; m < 2; ++m)
    #pragma unroll
    for (int i = 0; i < 8; i++) o[m][i] = floatx4{0.f, 0.f, 0.f, 0.f};
  float m2[2], lsum[2];
  m2[0] = m2[1] = -__builtin_inff();
  lsum[0] = lsum[1] = 0.f;

  auto stage = [&](int bi, int kt2) {
    const int kb2 = kt2 * 32;
    #pragma unroll
    for (int j = 0; j < 2; ++j) {
      int g  = j * 256 + t;
      int kr = g >> 4, ks = g & 15;              // K: 32 rows x 16 chunks
      gload16(kg + (size_t)(kb2 + kr) * HD + ((ks ^ (kr & 7)) << 3), &lsK[bi][g * 8]);
      int vr = g >> 2, vs = g & 3;               // V: 128 rows x 4 chunks
      gload16(vg + (size_t)vr * SS + kb2 + ((vs ^ (vr & 3)) << 3), &lsV[bi][g * 8]);
    }
  };

  const int ktiles = qblk * 4 + 4;
  stage(0, 0);

  const int e7 = l15 & 7;   // K-frag row-XOR

  for (int kt = 0; kt < ktiles; ++kt) {
    const int cur   = kt & 1;
    const int kbase = kt * 32;

    if (kt + 1 < ktiles) {
      stage(cur ^ 1, kt + 1);
      asm volatile("s_waitcnt vmcnt(4)" ::: "memory");
    } else {
      asm volatile("s_waitcnt vmcnt(0)" ::: "memory");
    }
    __builtin_amdgcn_s_barrier();   // current tile landed

    if (kbase <= qrow_w + 31) {
      // ---- swapped QK^T: S^T[k][q], 16 MFMAs ----
      floatx4 sa[2], sb[2];
      sa[0] = floatx4{0.f,0.f,0.f,0.f}; sa[1] = floatx4{0.f,0.f,0.f,0.f};
      sb[0] = floatx4{0.f,0.f,0.f,0.f}; sb[1] = floatx4{0.f,0.f,0.f,0.f};
      __builtin_amdgcn_s_setprio(1);
      #pragma unroll
      for (int c = 0; c < 4; ++c) {
        bf16x8 k0 = *reinterpret_cast<const bf16x8*>(
            &lsK[cur][l15 * 128 + (((c * 4 + lk) ^ e7) * 8)]);
        bf16x8 k1 = *reinterpret_cast<const bf16x8*>(
            &lsK[cur][(16 + l15) * 128 + (((c * 4 + lk) ^ e7) * 8)]);
        sa[0] = mfma16(k0, qf[0][c], sa[0]);
        sa[1] = mfma16(k0, qf[1][c], sa[1]);
        sb[0] = mfma16(k1, qf[0][c], sb[0]);
        sb[1] = mfma16(k1, qf[1][c], sb[1]);
      }
      __builtin_amdgcn_s_setprio(0);

      // ---- lane-local softmax (q = l15 within each m-tile) ----
      float alpha[2];
      #pragma unroll
      for (int m = 0; m < 2; ++m) {
        const int qrm = qrow_w + m * 16;
        const int q   = qrm + l15;
        if (kbase + 31 > qrm) {   // diagonal tile: causal mask (k > q -> -inf)
          #pragma unroll
          for (int r = 0; r < 4; r++) {
            if (kbase + lk * 4 + r > q)      sa[m][r] = -__builtin_inff();
            if (kbase + 16 + lk * 4 + r > q) sb[m][r] = -__builtin_inff();
          }
        }
        float mt = fmaxf(fmaxf(fmaxf(sa[m][0], sa[m][1]), fmaxf(sa[m][2], sa[m][3])),
                         fmaxf(fmaxf(sb[m][0], sb[m][1]), fmaxf(sb[m][2], sb[m][3])));
        mt = fmaxf(mt, __shfl_xor(mt, 16));
        mt = fmaxf(mt, __shfl_xor(mt, 32));
        float mo = m2[m];
        float mn = (mt > mo + 8.f) ? mt : mo;   // defer-max (T13)
        alpha[m] = EXP2F(mo - mn);               // exactly 1.0 when deferred
        m2[m] = mn;
        #pragma unroll
        for (int r = 0; r < 4; r++) {
          sa[m][r] = EXP2F(sa[m][r] - mn);
          sb[m][r] = EXP2F(sb[m][r] - mn);
        }
        float ps = ((sa[m][0] + sa[m][1]) + (sa[m][2] + sa[m][3]))
                 + ((sb[m][0] + sb[m][1]) + (sb[m][2] + sb[m][3]));
        ps += __shfl_xor(ps, 16);
        ps += __shfl_xor(ps, 32);
        lsum[m] = lsum[m] * alpha[m] + ps;

        // P^T pack & stash: row q=l15, cols {lk*4.., 16+lk*4..}
        uint16_t* pbuf = pls[w][m];
        uint2 w01 = { cvtpk(sa[m][0], sa[m][1]), cvtpk(sa[m][2], sa[m][3]) };
        uint2 w23 = { cvtpk(sb[m][0], sb[m][1]), cvtpk(sb[m][2], sb[m][3]) };
        *reinterpret_cast<uint2*>(&pbuf[l15 * 48 + lk * 4])      = w01;
        *reinterpret_cast<uint2*>(&pbuf[l15 * 48 + 16 + lk * 4]) = w23;
      }

      if (__any(alpha[0] != 1.f || alpha[1] != 1.f)) {
        #pragma unroll
        for (int m = 0; m < 2; ++m)
          #pragma unroll
          for (int i = 0; i < 8; i++)
            #pragma unroll
            for (int r = 0; r < 4; r++) o[m][i][r] *= alpha[m];
      }

      // P^T B-frag: col q = l15, k = lk*8+j  (contiguous row read)
      asm volatile("s_waitcnt lgkmcnt(0)" ::: "memory");
      bf16x8 pf0 = *reinterpret_cast<const bf16x8*>(&pls[w][0][l15 * 48 + lk * 8]);
      bf16x8 pf1 = *reinterpret_cast<const bf16x8*>(&pls[w][1][l15 * 48 + lk * 8]);

      // ---- PV as O^T = V^T * P^T: 16 MFMAs, V frags shared across m ----
      __builtin_amdgcn_s_setprio(1);
      #pragma unroll
      for (int i = 0; i < 8; i++) {
        int vrr = i * 16 + l15;
        bf16x8 vf = *reinterpret_cast<const bf16x8*>(
            &lsV[cur][vrr * 32 + ((lk ^ (vrr & 3)) * 8)]);
        o[0][i] = mfma16(vf, pf0, o[0][i]);
        o[1][i] = mfma16(vf, pf1, o[1][i]);
      }
      __builtin_amdgcn_s_setprio(0);
    }
    __builtin_amdgcn_s_barrier();   // all waves done with buf before reuse
  }

  // epilogue: O[q = qrow_w+m*16+l15][d = i*16+lk*4+r], packed 8B stores
  #pragma unroll
  for (int m = 0; m < 2; ++m) {
    float inv = 1.0f / lsum[m];
    uint16_t* base = ctxb + ((size_t)b * SS + qrow_w + m * 16 + l15) * HIDD
                   + h * HD + lk * 4;
    #pragma unroll
    for (int i = 0; i < 8; i++) {
      uint2 pr = { cvtpk(o[m][i][0] * inv, o[m][i][1] * inv),
                   cvtpk(o[m][i][2] * inv, o[m][i][3] * inv) };
      *reinterpret_cast<uint2*>(base + i * 16) = pr;
    }
  }
}

// ---------------- launch ----------------
extern "C" void kernel_launch(void* const* d_in, const int* in_sizes, int n_in,
                              void* d_out, int out_size, void* d_ws, size_t ws_size,
                              hipStream_t stream) {
  const float* x  = (const float*)d_in[0];
  const float* Wq = (const float*)d_in[1];
  const float* Wk = (const float*)d_in[2];
  const float* Wv = (const float*)d_in[3];
  const float* Wo = (const float*)d_in[4];
  float* out = (float*)d_out;
  float* kv  = out + (size_t)BB * SS * HIDD;  // kv cache region

  uint8_t* ws = (uint8_t*)d_ws;
  // byte offsets (total 160 MiB)
  uint16_t* xb  = (uint16_t*)(ws);              // 32 MiB; reused as ctx after attn
  uint16_t* qb  = (uint16_t*)(ws + 33554432);
  uint16_t* kb  = (uint16_t*)(ws + 67108864);
  uint16_t* vtb = (uint16_t*)(ws + 100663296);
  uint16_t* wqb = (uint16_t*)(ws + 134217728);  // wq,wk,wv,wo contiguous (4x8MB)
  uint16_t* wob = (uint16_t*)(ws + 159383552);

  cvt_f32_bf16<<<16384, 256, 0, stream>>>(x, xb);
  cvt_w4<<<16384, 256, 0, stream>>>(Wq, Wk, Wv, Wo, wqb);

  // fused QKV projection (mode 4): 48 col-blocks x 64 row-blocks
  gemm_bf16<<<3072, 256, 0, stream>>>(xb, wqb, qb, kb, vtb, kv, 4);

  attn_fwd<<<1024, 256, 0, stream>>>(qb, kb, vtb, xb /*ctx*/);

  // output projection (mode 3)
  gemm_bf16<<<1024, 256, 0, stream>>>(xb, wob, nullptr, nullptr, nullptr, out, 3);
}